// Round 9
// baseline (366.781 us; speedup 1.0000x reference)
//
#include <hip/hip_runtime.h>
#include <hip/hip_fp16.h>
#include <cmath>

#define BATCH 1024
#define SOUT 36336
#define POUT 10596
#define PS_COLS 10464   // s params compacted (dec2 block removed)
#define PP_COLS 10596
#define PD_COLS 25872   // s dec2 block (W 32x784 + b 784)

typedef __attribute__((ext_vector_type(8))) short bf16x8;
typedef __attribute__((ext_vector_type(4))) float f32x4;

__device__ __forceinline__ float sigmoidf_(float x){ return 1.0f/(1.0f+__expf(-x)); }
__device__ __forceinline__ float reluf_(float x){ return x>0.0f?x:0.0f; }

__device__ __forceinline__ void bf16split(float f, unsigned short& hi, unsigned short& lo){
  unsigned u = __float_as_uint(f);
  hi = (unsigned short)(u >> 16);
  float fhi = __uint_as_float(((unsigned)hi) << 16);
  float rem = f - fhi;                       // exact in fp32
  lo = (unsigned short)(__float_as_uint(rem) >> 16);
}

// ---------------- K1: backbone hidden h2 (s and p), emitted as bf16 hi/lo ---------
__global__ __launch_bounds__(128) void k_backbone(
    const float* __restrict__ z,
    const float* __restrict__ sw1, const float* __restrict__ sb1,
    const float* __restrict__ sw2, const float* __restrict__ sb2,
    const float* __restrict__ pw1, const float* __restrict__ pb1,
    const float* __restrict__ pw2, const float* __restrict__ pb2,
    unsigned short* __restrict__ h2s_hi, unsigned short* __restrict__ h2s_lo,
    unsigned short* __restrict__ h2p_hi, unsigned short* __restrict__ h2p_lo)
{
  __shared__ float zsh[32];
  __shared__ float h1sh[2][64];
  const int b = blockIdx.x;
  const int tid = threadIdx.x;
  const int g = tid >> 6, o = tid & 63;
  if (tid < 32) zsh[tid] = z[b*32 + tid];
  __syncthreads();
  const float* w1 = g ? pw1 : sw1;
  const float* b1 = g ? pb1 : sb1;
  float acc = b1[o];
  #pragma unroll
  for (int i=0;i<32;i++) acc += zsh[i]*w1[i*64+o];
  h1sh[g][o] = reluf_(acc);
  __syncthreads();
  const float* w2 = g ? pw2 : sw2;
  const float* b2 = g ? pb2 : sb2;
  float acc2 = b2[o];
  #pragma unroll
  for (int i=0;i<64;i++) acc2 += h1sh[g][i]*w2[i*64+o];
  float v = reluf_(acc2);
  unsigned short hi, lo;
  bf16split(v, hi, lo);
  (g ? h2p_hi : h2s_hi)[b*64+o] = hi;
  (g ? h2p_lo : h2s_lo)[b*64+o] = lo;
}

// ---------------- K2: all three params GEMMs on MFMA (bf16 hi/lo split) -----------
__global__ __launch_bounds__(256, 2) void k_params5(
    const unsigned short* __restrict__ h2s_hi, const unsigned short* __restrict__ h2s_lo,
    const unsigned short* __restrict__ h2p_hi, const unsigned short* __restrict__ h2p_lo,
    const float* __restrict__ sw3, const float* __restrict__ sb3,
    const float* __restrict__ pw3, const float* __restrict__ pb3,
    float* __restrict__ Ps, float* __restrict__ Pp, __half* __restrict__ Pd)
{
  __shared__ __align__(16) unsigned short wth[64][72];   // w3^T hi, padded
  __shared__ __align__(16) unsigned short wtl[64][72];   // w3^T lo
  int xt = blockIdx.x;
  const unsigned short *ahi, *alo;
  const float *w3, *b3;
  float* outF = nullptr; __half* outH = nullptr;
  int OC, thr, off, stride;
  if (xt < 164){
    ahi=h2s_hi; alo=h2s_lo; w3=sw3; b3=sb3; outF=Ps;
    OC=PS_COLS; thr=4192; off=25872; stride=SOUT;
  } else if (xt < 330){
    xt -= 164;
    ahi=h2p_hi; alo=h2p_lo; w3=pw3; b3=pb3; outF=Pp;
    OC=PP_COLS; thr=0x40000000; off=0; stride=POUT;
  } else {
    xt -= 330;
    ahi=h2s_hi; alo=h2s_lo; w3=sw3; b3=sb3; outH=Pd;
    OC=PD_COLS; thr=0; off=4192; stride=SOUT;
  }
  const int c0 = xt*64;
  const int tid = threadIdx.x;

  for (int idx=tid; idx<4096; idx+=256){
    int j = idx >> 6, cc = idx & 63;
    int c = c0 + cc; if (c > OC-1) c = OC-1;
    int src = (c < thr) ? c : c + off;
    float f = w3[(size_t)j*stride + src];
    unsigned short hi, lo;
    bf16split(f, hi, lo);
    wth[cc][j] = hi; wtl[cc][j] = lo;
  }
  __syncthreads();

  const int wv = tid >> 6, l = tid & 63;
  const int lr = l & 15, lq = l >> 4;

  bf16x8 Bh[2][4], Bl[2][4];
  #pragma unroll
  for (int ks=0; ks<2; ks++){
    #pragma unroll
    for (int ct=0; ct<4; ct++){
      const int row = ct*16 + lr;
      const int joff = ks*32 + lq*8;
      Bh[ks][ct] = *reinterpret_cast<const bf16x8*>(&wth[row][joff]);
      Bl[ks][ct] = *reinterpret_cast<const bf16x8*>(&wtl[row][joff]);
    }
  }
  float bv[4];
  #pragma unroll
  for (int ct=0; ct<4; ct++){
    int c = c0 + ct*16 + lr; if (c > OC-1) c = OC-1;
    int src = (c < thr) ? c : c + off;
    bv[ct] = b3[src];
  }

  for (int bsub=0; bsub<16; bsub++){
    const int arow = bsub*64 + wv*16 + lr;
    const unsigned short* ah = ahi + arow*64;
    const unsigned short* al = alo + arow*64;
    bf16x8 Ah0 = *reinterpret_cast<const bf16x8*>(ah + lq*8);
    bf16x8 Ah1 = *reinterpret_cast<const bf16x8*>(ah + 32 + lq*8);
    bf16x8 Al0 = *reinterpret_cast<const bf16x8*>(al + lq*8);
    bf16x8 Al1 = *reinterpret_cast<const bf16x8*>(al + 32 + lq*8);
    #pragma unroll
    for (int ct=0; ct<4; ct++){
      f32x4 acc = {0.f,0.f,0.f,0.f};
      acc = __builtin_amdgcn_mfma_f32_16x16x32_bf16(Ah0, Bh[0][ct], acc, 0,0,0);
      acc = __builtin_amdgcn_mfma_f32_16x16x32_bf16(Ah1, Bh[1][ct], acc, 0,0,0);
      acc = __builtin_amdgcn_mfma_f32_16x16x32_bf16(Ah0, Bl[0][ct], acc, 0,0,0);
      acc = __builtin_amdgcn_mfma_f32_16x16x32_bf16(Ah1, Bl[1][ct], acc, 0,0,0);
      acc = __builtin_amdgcn_mfma_f32_16x16x32_bf16(Al0, Bh[0][ct], acc, 0,0,0);
      acc = __builtin_amdgcn_mfma_f32_16x16x32_bf16(Al1, Bh[1][ct], acc, 0,0,0);
      const int c = c0 + ct*16 + lr;
      if (c < OC){
        const int r0 = bsub*64 + wv*16 + lq*4;
        const float bb = bv[ct];
        if (outF){
          outF[(size_t)(r0+0)*OC + c] = acc[0] + bb;
          outF[(size_t)(r0+1)*OC + c] = acc[1] + bb;
          outF[(size_t)(r0+2)*OC + c] = acc[2] + bb;
          outF[(size_t)(r0+3)*OC + c] = acc[3] + bb;
        } else {
          outH[(size_t)(r0+0)*OC + c] = __float2half(acc[0] + bb);
          outH[(size_t)(r0+1)*OC + c] = __float2half(acc[1] + bb);
          outH[(size_t)(r0+2)*OC + c] = __float2half(acc[2] + bb);
          outH[(size_t)(r0+3)*OC + c] = __float2half(acc[3] + bb);
        }
      }
    }
  }
}

// ---------------- K3: 20 sequential hyper-GRU step pairs ----------------
// 512 threads = 2 batch elems per block (single-round co-residency: 512 blocks,
// 2 blocks/CU). Register-resident weights; float4 LDS broadcast reads (4x fewer
// LDS issue slots). VGPR cap 128 (launch_bounds 512,4); measured need ~116.
__global__ __launch_bounds__(512, 4) void k_seq(
    const float* __restrict__ Ps, const float* __restrict__ Pp,
    float* __restrict__ Dout, float* __restrict__ Aout)
{
  __shared__ float xvT[2][64], xvI[2][64], initZ[2][64], hst[2][64];
  __shared__ float psA[2][128], e2s[2][64], gxs[2][128], ghs[2][128];
  __shared__ float rhs[2][64], d1s[2][32];

  const int tid = threadIdx.x;
  const int e  = tid >> 8;            // elem within block
  const int et = tid & 255;
  const int b  = blockIdx.x*2 + e;
  const int g  = et >> 7, lt = et & 127;
  const float* Gp = g ? (Pp + (size_t)b*PP_COLS) : (Ps + (size_t)b*PS_COLS);
  const int rnn = g ? 4324 : 4192;

  float wA[32], wB[32], wC[32];
  float bA = 0.f, bB = 0.f;
  {
    int baseA;
    if (lt < 64)       baseA = (lt>>5)*1024 + (lt&31);     // enc1 (64x32), K-half
    else if (lt < 96)  baseA = 2080 + (lt-64);             // enc2 (32x32)
    else               baseA = 3136 + (lt-96);             // dec1 (32x32)
    #pragma unroll
    for (int i=0;i<32;i++) wA[i] = Gp[baseA + i*32];
    if (lt < 32)                  bA = Gp[2048 + lt];
    else if (lt >= 64 && lt < 96) bA = Gp[3104 + (lt-64)];
    else if (lt >= 96)            bA = Gp[4160 + (lt-96)];
    if (lt < 96){
      #pragma unroll
      for (int i=0;i<32;i++) wB[i] = Gp[rnn + i*96 + lt];
      bB = Gp[rnn + 6144 + lt];
      #pragma unroll
      for (int i=0;i<32;i++) wC[i] = Gp[rnn + 3072 + i*96 + lt];
    } else if (g == 1 && lt < 100){
      #pragma unroll
      for (int i=0;i<32;i++) wB[i] = Gp[4192 + i*4 + (lt-96)];
      bB = Gp[4320 + (lt-96)];
    }
  }

  if (et < 64) hst[e][et] = 0.f;
  if (et < 32) initZ[e][et] = Ps[(size_t)b*PS_COLS + 10432 + et];
  else if (et < 64) initZ[e][et] = Pp[(size_t)b*PP_COLS + 10564 + (et-32)];
  __syncthreads();
  if (et < 64) xvT[e][et] = initZ[e][et];
  __syncthreads();

  auto substep = [&](const float (*xv)[64], int aidx, int t16, bool isTop){
    // A: e1 partial sums (lanes 0-63), float4 broadcast reads
    if (lt < 64){
      float a0 = (lt < 32) ? bA : 0.f, a1=0.f, a2=0.f, a3=0.f;
      const float4* x4 = reinterpret_cast<const float4*>(&xv[e][(lt>>5)*32]);
      #pragma unroll
      for (int i=0;i<8;i++){
        float4 v = x4[i];
        a0 += v.x*wA[4*i+0]; a1 += v.y*wA[4*i+1];
        a2 += v.z*wA[4*i+2]; a3 += v.w*wA[4*i+3];
      }
      psA[e][g*64 + lt] = (a0+a1)+(a2+a3);
    }
    __syncthreads();
    // B: e2 = relu(e1) @ Wenc2 + b (lanes 64-95)
    if (lt >= 64 && lt < 96){
      float a0=bA, a1=0.f, a2=0.f, a3=0.f;
      const float4* p0 = reinterpret_cast<const float4*>(&psA[e][g*64]);
      const float4* p1 = reinterpret_cast<const float4*>(&psA[e][g*64+32]);
      #pragma unroll
      for (int i=0;i<8;i++){
        float4 u = p0[i], v = p1[i];
        a0 += reluf_(u.x+v.x)*wA[4*i+0];
        a1 += reluf_(u.y+v.y)*wA[4*i+1];
        a2 += reluf_(u.z+v.z)*wA[4*i+2];
        a3 += reluf_(u.w+v.w)*wA[4*i+3];
      }
      e2s[e][g*32 + (lt-64)] = (a0+a1)+(a2+a3);
    }
    __syncthreads();
    // C: gx cols 0-63 + gh (lanes 0-63); xh cols 64-95 (lanes 64-95, reg)
    float xh = 0.f;
    if (lt < 64){
      float x0=bB, x1=0.f, h0=0.f, h1=0.f;
      const float4* e4 = reinterpret_cast<const float4*>(&e2s[e][g*32]);
      const float4* h4 = reinterpret_cast<const float4*>(&hst[e][g*32]);
      #pragma unroll
      for (int i=0;i<8;i++){
        float4 u = e4[i], v = h4[i];
        x0 += u.x*wB[4*i+0] + u.z*wB[4*i+2];
        x1 += u.y*wB[4*i+1] + u.w*wB[4*i+3];
        h0 += v.x*wC[4*i+0] + v.z*wC[4*i+2];
        h1 += v.y*wC[4*i+1] + v.w*wC[4*i+3];
      }
      gxs[e][g*64 + lt] = x0+x1;
      ghs[e][g*64 + lt] = h0+h1;
    } else if (lt < 96){
      float a0=bB, a1=0.f, a2=0.f, a3=0.f;
      const float4* e4 = reinterpret_cast<const float4*>(&e2s[e][g*32]);
      #pragma unroll
      for (int i=0;i<8;i++){
        float4 u = e4[i];
        a0 += u.x*wB[4*i+0]; a1 += u.y*wB[4*i+1];
        a2 += u.z*wB[4*i+2]; a3 += u.w*wB[4*i+3];
      }
      xh = (a0+a1)+(a2+a3);
    }
    __syncthreads();
    // DEF: gates + candidate + h-update (lanes 64-95); dec1/dec2 (lanes 96-127)
    if (lt >= 64 && lt < 96){
      int o = lt-64;
      float ho = hst[e][g*32+o];
      float zg = sigmoidf_(gxs[e][g*64+o]    + ghs[e][g*64+o]);
      float rg = sigmoidf_(gxs[e][g*64+32+o] + ghs[e][g*64+32+o]);
      rhs[e][g*32+o] = rg * ho;
      float a0=0.f, a1=0.f, a2=0.f, a3=0.f;
      const float4* r4 = reinterpret_cast<const float4*>(&rhs[e][g*32]);
      #pragma unroll
      for (int i=0;i<8;i++){
        float4 v = r4[i];
        a0 += v.x*wC[4*i+0]; a1 += v.y*wC[4*i+1];
        a2 += v.z*wC[4*i+2]; a3 += v.w*wC[4*i+3];
      }
      float hh = tanhf(xh + (a0+a1)+(a2+a3));
      float hn = zg*ho + (1.f-zg)*hh;
      hst[e][g*32+o] = hn;
      if (isTop) xvT[e][g*32+o] = hn; else xvI[e][g*32+o] = hn;
    }
    if (isTop && et < 64) xvI[e][et] = initZ[e][et];   // inner restarts from inits
    if (lt >= 96 && (g==1 || t16 >= 0)){
      int o = lt-96;
      float a0=bA, a1=0.f, a2=0.f, a3=0.f;
      const float4* h4 = reinterpret_cast<const float4*>(&hst[e][g*32]);
      #pragma unroll
      for (int i=0;i<8;i++){
        float4 v = h4[i];
        a0 += v.x*wA[4*i+0]; a1 += v.y*wA[4*i+1];
        a2 += v.z*wA[4*i+2]; a3 += v.w*wA[4*i+3];
      }
      float d = reluf_((a0+a1)+(a2+a3));
      if (g == 0) Dout[((size_t)t16*BATCH + b)*32 + o] = d;
      else d1s[e][o] = d;
    }
    if (g == 1 && lt >= 96 && lt < 100){
      int o = lt-96;
      float a0=bB, a1=0.f, a2=0.f, a3=0.f;
      const float4* d4 = reinterpret_cast<const float4*>(&d1s[e][0]);
      #pragma unroll
      for (int i=0;i<8;i++){
        float4 v = d4[i];
        a0 += v.x*wB[4*i+0]; a1 += v.y*wB[4*i+1];
        a2 += v.z*wB[4*i+2]; a3 += v.w*wB[4*i+3];
      }
      Aout[((size_t)aidx*BATCH + b)*4 + o] = (a0+a1)+(a2+a3);
    }
    __syncthreads();
  };

  for (int t=0;t<4;t++){
    substep(xvT, t, -1, true);
    for (int k=0;k<4;k++){
      substep(xvI, 4 + t*4 + k, t*4 + k, false);
    }
  }
}

// ---------------- bilinear samplers (fp32 and fp16 LDS images) ----------------
__device__ __forceinline__ float fetchpix(const float* __restrict__ img, int y, int x){
  if ((unsigned)y >= 28u || (unsigned)x >= 28u) return 0.0f;
  return img[y*28 + x];
}
__device__ __forceinline__ float fetchpixh(const __half* __restrict__ img, int y, int x){
  if ((unsigned)y >= 28u || (unsigned)x >= 28u) return 0.0f;
  return __half2float(img[y*28 + x]);
}
#define BILIN_BODY(FETCH) \
  const float stepv = 2.0f/27.0f; \
  float gxv = -1.0f + stepv*(float)c; \
  float gyv = -1.0f + stepv*(float)r; \
  float srcx = (a0 + 1.0f)*gxv + a2; \
  float srcy = (a1 + 1.0f)*gyv + a3; \
  float px = (srcx + 1.0f)*13.5f; \
  float py = (srcy + 1.0f)*13.5f; \
  float x0f = floorf(px), y0f = floorf(py); \
  float wx = px - x0f, wy = py - y0f; \
  int x0 = (int)x0f, y0 = (int)y0f; \
  float v00 = FETCH(img, y0,   x0); \
  float v01 = FETCH(img, y0,   x0+1); \
  float v10 = FETCH(img, y0+1, x0); \
  float v11 = FETCH(img, y0+1, x0+1); \
  return v00*(1.0f-wx)*(1.0f-wy) + v01*wx*(1.0f-wy) \
       + v10*(1.0f-wx)*wy + v11*wx*wy;

__device__ __forceinline__ float bilin(const float* __restrict__ img,
    float a0, float a1, float a2, float a3, int r, int c){ BILIN_BODY(fetchpix) }
__device__ __forceinline__ float bilinh(const __half* __restrict__ img,
    float a0, float a1, float a2, float a3, int r, int c){ BILIN_BODY(fetchpixh) }

// ---------------- K4: fused decode: xhat (fp16 Pd stream) + both composites --------
// xh images stored fp16 in LDS -> 40 KB/block -> 4 blocks/CU, single round.
__global__ __launch_bounds__(256, 4) void k_dec(
    const __half* __restrict__ Pd, const float* __restrict__ Dm,
    const float* __restrict__ Am, float* __restrict__ outp)
{
  extern __shared__ float lds[];
  float*  o0 = lds;                                      // 3136 f32
  float*  Da = lds + 3136;                               // 528
  float*  av = lds + 3664;                               // 80
  __half* xh = reinterpret_cast<__half*>(lds + 3744);    // 16*784 halves (25088 B)
  const int b = blockIdx.x;
  const int tid = threadIdx.x;

  for (int idx=tid; idx<512; idx+=256){
    int t = idx >> 5, i = idx & 31;
    Da[t*33 + i] = Dm[((size_t)t*BATCH + b)*32 + i];
  }
  if (tid < 16) Da[tid*33 + 32] = 1.0f;
  if (tid < 80) av[tid] = Am[((size_t)(tid>>2)*BATCH + b)*4 + (tid&3)];

  float4 acc4[16];
  #pragma unroll
  for (int t=0;t<16;t++) acc4[t] = make_float4(0.f,0.f,0.f,0.f);
  __syncthreads();

  const __half* Pdb = Pd + (size_t)b*PD_COLS;
  #pragma unroll 3
  for (int i=0;i<33;i++){
    const __half* row = Pdb + (i<32 ? i*784 : 25088);
    float4 v = make_float4(0.f,0.f,0.f,0.f);
    if (tid < 196){
      const __half2 h0 = reinterpret_cast<const __half2*>(row)[tid*2];
      const __half2 h1 = reinterpret_cast<const __half2*>(row)[tid*2+1];
      float2 f0 = __half22float2(h0), f1 = __half22float2(h1);
      v = make_float4(f0.x, f0.y, f1.x, f1.y);
    }
    #pragma unroll
    for (int t=0;t<16;t++){
      float da = Da[t*33 + i];
      acc4[t].x += da*v.x; acc4[t].y += da*v.y;
      acc4[t].z += da*v.z; acc4[t].w += da*v.w;
    }
  }
  if (tid < 196){
    #pragma unroll
    for (int t=0;t<16;t++){
      __half2* dst = reinterpret_cast<__half2*>(xh + t*784 + tid*4);
      dst[0] = __floats2half2_rn(acc4[t].x, acc4[t].y);
      dst[1] = __floats2half2_rn(acc4[t].z, acc4[t].w);
    }
  }
  __syncthreads();

  // level-0 composite
  for (int idx=tid; idx<4*784; idx+=256){
    int t = idx / 784, pix = idx - t*784;
    int r = pix / 28, c = pix - r*28;
    float s = 0.f;
    #pragma unroll
    for (int k=0;k<4;k++){
      const float* ap = av + (4 + t*4 + k)*4;
      s += bilinh(xh + (t*4+k)*784, ap[0], ap[1], ap[2], ap[3], r, c);
    }
    o0[t*784 + pix] = s;
  }
  __syncthreads();

  // level-1 composite -> d_out
  for (int idx=tid; idx<784; idx+=256){
    int r = idx / 28, c = idx - r*28;
    float s = 0.f;
    #pragma unroll
    for (int t=0;t<4;t++){
      const float* ap = av + t*4;
      s += bilin(o0 + t*784, ap[0], ap[1], ap[2], ap[3], r, c);
    }
    outp[(size_t)b*784 + idx] = s;
  }
}

extern "C" void kernel_launch(void* const* d_in, const int* in_sizes, int n_in,
                              void* d_out, int out_size, void* d_ws, size_t ws_size,
                              hipStream_t stream)
{
  const float* z   = (const float*)d_in[1];
  const float* sw1 = (const float*)d_in[2];
  const float* sb1 = (const float*)d_in[3];
  const float* sw2 = (const float*)d_in[4];
  const float* sb2 = (const float*)d_in[5];
  const float* sw3 = (const float*)d_in[6];
  const float* sb3 = (const float*)d_in[7];
  const float* pw1 = (const float*)d_in[8];
  const float* pb1 = (const float*)d_in[9];
  const float* pw2 = (const float*)d_in[10];
  const float* pb2 = (const float*)d_in[11];
  const float* pw3 = (const float*)d_in[12];
  const float* pb3 = (const float*)d_in[13];

  float* ws = (float*)d_ws;
  float*  Ps = ws;                                   // 1024*10464
  float*  Pp = ws + 10715136;                        // 1024*10596
  __half* Pd = (__half*)(ws + 21565440);             // 1024*25872 halves
  float*  Dm = ws + 34811904;                        // 16*1024*32
  float*  Am = ws + 35336192;                        // 20*1024*4
  unsigned short* h2s_hi = (unsigned short*)(ws + 35418112);   // 1024*64 each
  unsigned short* h2s_lo = h2s_hi + 65536;
  unsigned short* h2p_hi = h2s_hi + 131072;
  unsigned short* h2p_lo = h2s_hi + 196608;
  float* outp = (float*)d_out;

  (void)hipFuncSetAttribute(reinterpret_cast<const void*>(k_dec),
                            hipFuncAttributeMaxDynamicSharedMemorySize,
                            40064);

  hipLaunchKernelGGL(k_backbone, dim3(1024), dim3(128), 0, stream,
                     z, sw1,sb1,sw2,sb2, pw1,pb1,pw2,pb2,
                     h2s_hi, h2s_lo, h2p_hi, h2p_lo);
  hipLaunchKernelGGL(k_params5, dim3(735), dim3(256), 0, stream,
                     h2s_hi, h2s_lo, h2p_hi, h2p_lo,
                     sw3, sb3, pw3, pb3, Ps, Pp, Pd);
  hipLaunchKernelGGL(k_seq, dim3(512), dim3(512), 0, stream,
                     Ps, Pp, Dm, Am);
  hipLaunchKernelGGL(k_dec, dim3(1024), dim3(256), 40064, stream,
                     Pd, Dm, Am, outp);
}

// Round 10
// 172.137 us; speedup vs baseline: 2.1308x; 2.1308x over previous
//
#include <hip/hip_runtime.h>
#include <hip/hip_fp16.h>
#include <cmath>

#define BATCH 1024
#define SOUT 36336
#define POUT 10596
#define PS_COLS 10464   // s params compacted (dec2 block removed)
#define PP_COLS 10596
#define PD_COLS 25872   // s dec2 block (W 32x784 + b 784)

typedef __attribute__((ext_vector_type(8))) short bf16x8;
typedef __attribute__((ext_vector_type(4))) float f32x4;

__device__ __forceinline__ float sigmoidf_(float x){ return 1.0f/(1.0f+__expf(-x)); }
__device__ __forceinline__ float reluf_(float x){ return x>0.0f?x:0.0f; }

__device__ __forceinline__ void bf16split(float f, unsigned short& hi, unsigned short& lo){
  unsigned u = __float_as_uint(f);
  hi = (unsigned short)(u >> 16);
  float fhi = __uint_as_float(((unsigned)hi) << 16);
  float rem = f - fhi;                       // exact in fp32
  lo = (unsigned short)(__float_as_uint(rem) >> 16);
}

// ---------------- K1: backbone hidden h2 (s and p), emitted as bf16 hi/lo ---------
__global__ __launch_bounds__(128) void k_backbone(
    const float* __restrict__ z,
    const float* __restrict__ sw1, const float* __restrict__ sb1,
    const float* __restrict__ sw2, const float* __restrict__ sb2,
    const float* __restrict__ pw1, const float* __restrict__ pb1,
    const float* __restrict__ pw2, const float* __restrict__ pb2,
    unsigned short* __restrict__ h2s_hi, unsigned short* __restrict__ h2s_lo,
    unsigned short* __restrict__ h2p_hi, unsigned short* __restrict__ h2p_lo)
{
  __shared__ float zsh[32];
  __shared__ float h1sh[2][64];
  const int b = blockIdx.x;
  const int tid = threadIdx.x;
  const int g = tid >> 6, o = tid & 63;
  if (tid < 32) zsh[tid] = z[b*32 + tid];
  __syncthreads();
  const float* w1 = g ? pw1 : sw1;
  const float* b1 = g ? pb1 : sb1;
  float acc = b1[o];
  #pragma unroll
  for (int i=0;i<32;i++) acc += zsh[i]*w1[i*64+o];
  h1sh[g][o] = reluf_(acc);
  __syncthreads();
  const float* w2 = g ? pw2 : sw2;
  const float* b2 = g ? pb2 : sb2;
  float acc2 = b2[o];
  #pragma unroll
  for (int i=0;i<64;i++) acc2 += h1sh[g][i]*w2[i*64+o];
  float v = reluf_(acc2);
  unsigned short hi, lo;
  bf16split(v, hi, lo);
  (g ? h2p_hi : h2s_hi)[b*64+o] = hi;
  (g ? h2p_lo : h2s_lo)[b*64+o] = lo;
}

// ---------------- K2: all three params GEMMs on MFMA (bf16 hi/lo split) -----------
__global__ __launch_bounds__(256, 2) void k_params5(
    const unsigned short* __restrict__ h2s_hi, const unsigned short* __restrict__ h2s_lo,
    const unsigned short* __restrict__ h2p_hi, const unsigned short* __restrict__ h2p_lo,
    const float* __restrict__ sw3, const float* __restrict__ sb3,
    const float* __restrict__ pw3, const float* __restrict__ pb3,
    float* __restrict__ Ps, float* __restrict__ Pp, __half* __restrict__ Pd)
{
  __shared__ __align__(16) unsigned short wth[64][72];   // w3^T hi, padded
  __shared__ __align__(16) unsigned short wtl[64][72];   // w3^T lo
  int xt = blockIdx.x;
  const unsigned short *ahi, *alo;
  const float *w3, *b3;
  float* outF = nullptr; __half* outH = nullptr;
  int OC, thr, off, stride;
  if (xt < 164){
    ahi=h2s_hi; alo=h2s_lo; w3=sw3; b3=sb3; outF=Ps;
    OC=PS_COLS; thr=4192; off=25872; stride=SOUT;
  } else if (xt < 330){
    xt -= 164;
    ahi=h2p_hi; alo=h2p_lo; w3=pw3; b3=pb3; outF=Pp;
    OC=PP_COLS; thr=0x40000000; off=0; stride=POUT;
  } else {
    xt -= 330;
    ahi=h2s_hi; alo=h2s_lo; w3=sw3; b3=sb3; outH=Pd;
    OC=PD_COLS; thr=0; off=4192; stride=SOUT;
  }
  const int c0 = xt*64;
  const int tid = threadIdx.x;

  for (int idx=tid; idx<4096; idx+=256){
    int j = idx >> 6, cc = idx & 63;
    int c = c0 + cc; if (c > OC-1) c = OC-1;
    int src = (c < thr) ? c : c + off;
    float f = w3[(size_t)j*stride + src];
    unsigned short hi, lo;
    bf16split(f, hi, lo);
    wth[cc][j] = hi; wtl[cc][j] = lo;
  }
  __syncthreads();

  const int wv = tid >> 6, l = tid & 63;
  const int lr = l & 15, lq = l >> 4;

  bf16x8 Bh[2][4], Bl[2][4];
  #pragma unroll
  for (int ks=0; ks<2; ks++){
    #pragma unroll
    for (int ct=0; ct<4; ct++){
      const int row = ct*16 + lr;
      const int joff = ks*32 + lq*8;
      Bh[ks][ct] = *reinterpret_cast<const bf16x8*>(&wth[row][joff]);
      Bl[ks][ct] = *reinterpret_cast<const bf16x8*>(&wtl[row][joff]);
    }
  }
  float bv[4];
  #pragma unroll
  for (int ct=0; ct<4; ct++){
    int c = c0 + ct*16 + lr; if (c > OC-1) c = OC-1;
    int src = (c < thr) ? c : c + off;
    bv[ct] = b3[src];
  }

  for (int bsub=0; bsub<16; bsub++){
    const int arow = bsub*64 + wv*16 + lr;
    const unsigned short* ah = ahi + arow*64;
    const unsigned short* al = alo + arow*64;
    bf16x8 Ah0 = *reinterpret_cast<const bf16x8*>(ah + lq*8);
    bf16x8 Ah1 = *reinterpret_cast<const bf16x8*>(ah + 32 + lq*8);
    bf16x8 Al0 = *reinterpret_cast<const bf16x8*>(al + lq*8);
    bf16x8 Al1 = *reinterpret_cast<const bf16x8*>(al + 32 + lq*8);
    #pragma unroll
    for (int ct=0; ct<4; ct++){
      f32x4 acc = {0.f,0.f,0.f,0.f};
      acc = __builtin_amdgcn_mfma_f32_16x16x32_bf16(Ah0, Bh[0][ct], acc, 0,0,0);
      acc = __builtin_amdgcn_mfma_f32_16x16x32_bf16(Ah1, Bh[1][ct], acc, 0,0,0);
      acc = __builtin_amdgcn_mfma_f32_16x16x32_bf16(Ah0, Bl[0][ct], acc, 0,0,0);
      acc = __builtin_amdgcn_mfma_f32_16x16x32_bf16(Ah1, Bl[1][ct], acc, 0,0,0);
      acc = __builtin_amdgcn_mfma_f32_16x16x32_bf16(Al0, Bh[0][ct], acc, 0,0,0);
      acc = __builtin_amdgcn_mfma_f32_16x16x32_bf16(Al1, Bh[1][ct], acc, 0,0,0);
      const int c = c0 + ct*16 + lr;
      if (c < OC){
        const int r0 = bsub*64 + wv*16 + lq*4;
        const float bb = bv[ct];
        if (outF){
          outF[(size_t)(r0+0)*OC + c] = acc[0] + bb;
          outF[(size_t)(r0+1)*OC + c] = acc[1] + bb;
          outF[(size_t)(r0+2)*OC + c] = acc[2] + bb;
          outF[(size_t)(r0+3)*OC + c] = acc[3] + bb;
        } else {
          outH[(size_t)(r0+0)*OC + c] = __float2half(acc[0] + bb);
          outH[(size_t)(r0+1)*OC + c] = __float2half(acc[1] + bb);
          outH[(size_t)(r0+2)*OC + c] = __float2half(acc[2] + bb);
          outH[(size_t)(r0+3)*OC + c] = __float2half(acc[3] + bb);
        }
      }
    }
  }
}

// ---------------- K3: 20 sequential hyper-GRU step pairs ----------------
// R8 config (256 threads, 1 elem/block, launch_bounds(256,2) -> VGPR cap 256,
// no spill) + float4 LDS broadcast reads (4x fewer LDS issue slots).
__global__ __launch_bounds__(256, 2) void k_seq(
    const float* __restrict__ Ps, const float* __restrict__ Pp,
    float* __restrict__ Dout, float* __restrict__ Aout)
{
  __shared__ float xvT[64], xvI[64], initZ[64], hst[64];
  __shared__ float psA[128], e2s[64], gxs[128], ghs[128];
  __shared__ float rhs[64], d1s[32];

  const int b = blockIdx.x;
  const int tid = threadIdx.x;
  const int g = tid >> 7, lt = tid & 127;
  const float* Gp = g ? (Pp + (size_t)b*PP_COLS) : (Ps + (size_t)b*PS_COLS);
  const int rnn = g ? 4324 : 4192;

  float wA[32], wB[32], wC[32];
  float bA = 0.f, bB = 0.f;
  {
    int baseA;
    if (lt < 64)       baseA = (lt>>5)*1024 + (lt&31);     // enc1 (64x32), K-half
    else if (lt < 96)  baseA = 2080 + (lt-64);             // enc2 (32x32)
    else               baseA = 3136 + (lt-96);             // dec1 (32x32)
    #pragma unroll
    for (int i=0;i<32;i++) wA[i] = Gp[baseA + i*32];
    if (lt < 32)                  bA = Gp[2048 + lt];
    else if (lt >= 64 && lt < 96) bA = Gp[3104 + (lt-64)];
    else if (lt >= 96)            bA = Gp[4160 + (lt-96)];
    if (lt < 96){
      #pragma unroll
      for (int i=0;i<32;i++) wB[i] = Gp[rnn + i*96 + lt];
      bB = Gp[rnn + 6144 + lt];
      #pragma unroll
      for (int i=0;i<32;i++) wC[i] = Gp[rnn + 3072 + i*96 + lt];
    } else if (g == 1 && lt < 100){
      #pragma unroll
      for (int i=0;i<32;i++) wB[i] = Gp[4192 + i*4 + (lt-96)];
      bB = Gp[4320 + (lt-96)];
    }
  }

  if (tid < 64) hst[tid] = 0.f;
  if (tid < 32) initZ[tid] = Ps[(size_t)b*PS_COLS + 10432 + tid];
  else if (tid < 64) initZ[tid] = Pp[(size_t)b*PP_COLS + 10564 + (tid-32)];
  __syncthreads();
  if (tid < 64) xvT[tid] = initZ[tid];
  __syncthreads();

  auto substep = [&](const float* xv, int aidx, int t16, bool isTop){
    // A: e1 partial sums (lanes 0-63), float4 broadcast reads
    if (lt < 64){
      float a0 = (lt < 32) ? bA : 0.f, a1=0.f, a2=0.f, a3=0.f;
      const float4* x4 = reinterpret_cast<const float4*>(&xv[(lt>>5)*32]);
      #pragma unroll
      for (int i=0;i<8;i++){
        float4 v = x4[i];
        a0 += v.x*wA[4*i+0]; a1 += v.y*wA[4*i+1];
        a2 += v.z*wA[4*i+2]; a3 += v.w*wA[4*i+3];
      }
      psA[g*64 + lt] = (a0+a1)+(a2+a3);
    }
    __syncthreads();
    // B: e2 = relu(e1) @ Wenc2 + b (lanes 64-95)
    if (lt >= 64 && lt < 96){
      float a0=bA, a1=0.f, a2=0.f, a3=0.f;
      const float4* p0 = reinterpret_cast<const float4*>(&psA[g*64]);
      const float4* p1 = reinterpret_cast<const float4*>(&psA[g*64+32]);
      #pragma unroll
      for (int i=0;i<8;i++){
        float4 u = p0[i], v = p1[i];
        a0 += reluf_(u.x+v.x)*wA[4*i+0];
        a1 += reluf_(u.y+v.y)*wA[4*i+1];
        a2 += reluf_(u.z+v.z)*wA[4*i+2];
        a3 += reluf_(u.w+v.w)*wA[4*i+3];
      }
      e2s[g*32 + (lt-64)] = (a0+a1)+(a2+a3);
    }
    __syncthreads();
    // C: gx cols 0-63 + gh (lanes 0-63); xh cols 64-95 (lanes 64-95, reg)
    float xh = 0.f;
    if (lt < 64){
      float x0=bB, x1=0.f, h0=0.f, h1=0.f;
      const float4* e4 = reinterpret_cast<const float4*>(&e2s[g*32]);
      const float4* h4 = reinterpret_cast<const float4*>(&hst[g*32]);
      #pragma unroll
      for (int i=0;i<8;i++){
        float4 u = e4[i], v = h4[i];
        x0 += u.x*wB[4*i+0] + u.z*wB[4*i+2];
        x1 += u.y*wB[4*i+1] + u.w*wB[4*i+3];
        h0 += v.x*wC[4*i+0] + v.z*wC[4*i+2];
        h1 += v.y*wC[4*i+1] + v.w*wC[4*i+3];
      }
      gxs[g*64 + lt] = x0+x1;
      ghs[g*64 + lt] = h0+h1;
    } else if (lt < 96){
      float a0=bB, a1=0.f, a2=0.f, a3=0.f;
      const float4* e4 = reinterpret_cast<const float4*>(&e2s[g*32]);
      #pragma unroll
      for (int i=0;i<8;i++){
        float4 u = e4[i];
        a0 += u.x*wB[4*i+0]; a1 += u.y*wB[4*i+1];
        a2 += u.z*wB[4*i+2]; a3 += u.w*wB[4*i+3];
      }
      xh = (a0+a1)+(a2+a3);
    }
    __syncthreads();
    // DEF: gates + candidate + h-update (lanes 64-95); dec1/dec2 (lanes 96-127)
    if (lt >= 64 && lt < 96){
      int o = lt-64;
      float ho = hst[g*32+o];
      float zg = sigmoidf_(gxs[g*64+o]    + ghs[g*64+o]);
      float rg = sigmoidf_(gxs[g*64+32+o] + ghs[g*64+32+o]);
      rhs[g*32+o] = rg * ho;
      float a0=0.f, a1=0.f, a2=0.f, a3=0.f;
      const float4* r4 = reinterpret_cast<const float4*>(&rhs[g*32]);
      #pragma unroll
      for (int i=0;i<8;i++){
        float4 v = r4[i];
        a0 += v.x*wC[4*i+0]; a1 += v.y*wC[4*i+1];
        a2 += v.z*wC[4*i+2]; a3 += v.w*wC[4*i+3];
      }
      float hh = tanhf(xh + (a0+a1)+(a2+a3));
      float hn = zg*ho + (1.f-zg)*hh;
      hst[g*32+o] = hn;
      if (isTop) xvT[g*32+o] = hn; else xvI[g*32+o] = hn;
    }
    if (isTop && tid < 64) xvI[tid] = initZ[tid];   // inner restarts from inits
    if (lt >= 96 && (g==1 || t16 >= 0)){
      int o = lt-96;
      float a0=bA, a1=0.f, a2=0.f, a3=0.f;
      const float4* h4 = reinterpret_cast<const float4*>(&hst[g*32]);
      #pragma unroll
      for (int i=0;i<8;i++){
        float4 v = h4[i];
        a0 += v.x*wA[4*i+0]; a1 += v.y*wA[4*i+1];
        a2 += v.z*wA[4*i+2]; a3 += v.w*wA[4*i+3];
      }
      float d = reluf_((a0+a1)+(a2+a3));
      if (g == 0) Dout[((size_t)t16*BATCH + b)*32 + o] = d;
      else d1s[o] = d;
    }
    if (g == 1 && lt >= 96 && lt < 100){
      int o = lt-96;
      float a0=bB, a1=0.f, a2=0.f, a3=0.f;
      const float4* d4 = reinterpret_cast<const float4*>(&d1s[0]);
      #pragma unroll
      for (int i=0;i<8;i++){
        float4 v = d4[i];
        a0 += v.x*wB[4*i+0]; a1 += v.y*wB[4*i+1];
        a2 += v.z*wB[4*i+2]; a3 += v.w*wB[4*i+3];
      }
      Aout[((size_t)aidx*BATCH + b)*4 + o] = (a0+a1)+(a2+a3);
    }
    __syncthreads();
  };

  for (int t=0;t<4;t++){
    substep(xvT, t, -1, true);
    for (int k=0;k<4;k++){
      substep(xvI, 4 + t*4 + k, t*4 + k, false);
    }
  }
}

// ---------------- bilinear samplers (fp32 and fp16 LDS images) ----------------
__device__ __forceinline__ float fetchpix(const float* __restrict__ img, int y, int x){
  if ((unsigned)y >= 28u || (unsigned)x >= 28u) return 0.0f;
  return img[y*28 + x];
}
__device__ __forceinline__ float fetchpixh(const __half* __restrict__ img, int y, int x){
  if ((unsigned)y >= 28u || (unsigned)x >= 28u) return 0.0f;
  return __half2float(img[y*28 + x]);
}
#define BILIN_BODY(FETCH) \
  const float stepv = 2.0f/27.0f; \
  float gxv = -1.0f + stepv*(float)c; \
  float gyv = -1.0f + stepv*(float)r; \
  float srcx = (a0 + 1.0f)*gxv + a2; \
  float srcy = (a1 + 1.0f)*gyv + a3; \
  float px = (srcx + 1.0f)*13.5f; \
  float py = (srcy + 1.0f)*13.5f; \
  float x0f = floorf(px), y0f = floorf(py); \
  float wx = px - x0f, wy = py - y0f; \
  int x0 = (int)x0f, y0 = (int)y0f; \
  float v00 = FETCH(img, y0,   x0); \
  float v01 = FETCH(img, y0,   x0+1); \
  float v10 = FETCH(img, y0+1, x0); \
  float v11 = FETCH(img, y0+1, x0+1); \
  return v00*(1.0f-wx)*(1.0f-wy) + v01*wx*(1.0f-wy) \
       + v10*(1.0f-wx)*wy + v11*wx*wy;

__device__ __forceinline__ float bilin(const float* __restrict__ img,
    float a0, float a1, float a2, float a3, int r, int c){ BILIN_BODY(fetchpix) }
__device__ __forceinline__ float bilinh(const __half* __restrict__ img,
    float a0, float a1, float a2, float a3, int r, int c){ BILIN_BODY(fetchpixh) }

// ---------------- K4: fused decode: xhat (fp16 Pd stream) + both composites --------
// xh images stored fp16 in LDS -> ~40 KB/block -> 4 blocks/CU.
__global__ __launch_bounds__(256, 4) void k_dec(
    const __half* __restrict__ Pd, const float* __restrict__ Dm,
    const float* __restrict__ Am, float* __restrict__ outp)
{
  extern __shared__ float lds[];
  float*  o0 = lds;                                      // 3136 f32
  float*  Da = lds + 3136;                               // 528
  float*  av = lds + 3664;                               // 80
  __half* xh = reinterpret_cast<__half*>(lds + 3744);    // 16*784 halves (25088 B)
  const int b = blockIdx.x;
  const int tid = threadIdx.x;

  for (int idx=tid; idx<512; idx+=256){
    int t = idx >> 5, i = idx & 31;
    Da[t*33 + i] = Dm[((size_t)t*BATCH + b)*32 + i];
  }
  if (tid < 16) Da[tid*33 + 32] = 1.0f;
  if (tid < 80) av[tid] = Am[((size_t)(tid>>2)*BATCH + b)*4 + (tid&3)];

  float4 acc4[16];
  #pragma unroll
  for (int t=0;t<16;t++) acc4[t] = make_float4(0.f,0.f,0.f,0.f);
  __syncthreads();

  const __half* Pdb = Pd + (size_t)b*PD_COLS;
  #pragma unroll 3
  for (int i=0;i<33;i++){
    const __half* row = Pdb + (i<32 ? i*784 : 25088);
    float4 v = make_float4(0.f,0.f,0.f,0.f);
    if (tid < 196){
      const __half2 h0 = reinterpret_cast<const __half2*>(row)[tid*2];
      const __half2 h1 = reinterpret_cast<const __half2*>(row)[tid*2+1];
      float2 f0 = __half22float2(h0), f1 = __half22float2(h1);
      v = make_float4(f0.x, f0.y, f1.x, f1.y);
    }
    #pragma unroll
    for (int t=0;t<16;t++){
      float da = Da[t*33 + i];
      acc4[t].x += da*v.x; acc4[t].y += da*v.y;
      acc4[t].z += da*v.z; acc4[t].w += da*v.w;
    }
  }
  if (tid < 196){
    #pragma unroll
    for (int t=0;t<16;t++){
      __half2* dst = reinterpret_cast<__half2*>(xh + t*784 + tid*4);
      dst[0] = __floats2half2_rn(acc4[t].x, acc4[t].y);
      dst[1] = __floats2half2_rn(acc4[t].z, acc4[t].w);
    }
  }
  __syncthreads();

  // level-0 composite
  for (int idx=tid; idx<4*784; idx+=256){
    int t = idx / 784, pix = idx - t*784;
    int r = pix / 28, c = pix - r*28;
    float s = 0.f;
    #pragma unroll
    for (int k=0;k<4;k++){
      const float* ap = av + (4 + t*4 + k)*4;
      s += bilinh(xh + (t*4+k)*784, ap[0], ap[1], ap[2], ap[3], r, c);
    }
    o0[t*784 + pix] = s;
  }
  __syncthreads();

  // level-1 composite -> d_out
  for (int idx=tid; idx<784; idx+=256){
    int r = idx / 28, c = idx - r*28;
    float s = 0.f;
    #pragma unroll
    for (int t=0;t<4;t++){
      const float* ap = av + t*4;
      s += bilin(o0 + t*784, ap[0], ap[1], ap[2], ap[3], r, c);
    }
    outp[(size_t)b*784 + idx] = s;
  }
}

extern "C" void kernel_launch(void* const* d_in, const int* in_sizes, int n_in,
                              void* d_out, int out_size, void* d_ws, size_t ws_size,
                              hipStream_t stream)
{
  const float* z   = (const float*)d_in[1];
  const float* sw1 = (const float*)d_in[2];
  const float* sb1 = (const float*)d_in[3];
  const float* sw2 = (const float*)d_in[4];
  const float* sb2 = (const float*)d_in[5];
  const float* sw3 = (const float*)d_in[6];
  const float* sb3 = (const float*)d_in[7];
  const float* pw1 = (const float*)d_in[8];
  const float* pb1 = (const float*)d_in[9];
  const float* pw2 = (const float*)d_in[10];
  const float* pb2 = (const float*)d_in[11];
  const float* pw3 = (const float*)d_in[12];
  const float* pb3 = (const float*)d_in[13];

  float* ws = (float*)d_ws;
  float*  Ps = ws;                                   // 1024*10464
  float*  Pp = ws + 10715136;                        // 1024*10596
  __half* Pd = (__half*)(ws + 21565440);             // 1024*25872 halves
  float*  Dm = ws + 34811904;                        // 16*1024*32
  float*  Am = ws + 35336192;                        // 20*1024*4
  unsigned short* h2s_hi = (unsigned short*)(ws + 35418112);   // 1024*64 each
  unsigned short* h2s_lo = h2s_hi + 65536;
  unsigned short* h2p_hi = h2s_hi + 131072;
  unsigned short* h2p_lo = h2s_hi + 196608;
  float* outp = (float*)d_out;

  (void)hipFuncSetAttribute(reinterpret_cast<const void*>(k_dec),
                            hipFuncAttributeMaxDynamicSharedMemorySize,
                            40064);

  hipLaunchKernelGGL(k_backbone, dim3(1024), dim3(128), 0, stream,
                     z, sw1,sb1,sw2,sb2, pw1,pb1,pw2,pb2,
                     h2s_hi, h2s_lo, h2p_hi, h2p_lo);
  hipLaunchKernelGGL(k_params5, dim3(735), dim3(256), 0, stream,
                     h2s_hi, h2s_lo, h2p_hi, h2p_lo,
                     sw3, sb3, pw3, pb3, Ps, Pp, Pd);
  hipLaunchKernelGGL(k_seq, dim3(1024), dim3(256), 0, stream,
                     Ps, Pp, Dm, Am);
  hipLaunchKernelGGL(k_dec, dim3(1024), dim3(256), 40064, stream,
                     Pd, Dm, Am, outp);
}